// Round 9
// baseline (817.975 us; speedup 1.0000x reference)
//
#include <hip/hip_runtime.h>
#include <math.h>

#define N_NODES 100000
#define N_EDGES 1200000
#define GC 64
#define RBF 32
#define NLAYERS 4
#define NF 92
#define NATOM 100
#define BN_EPS 1e-5f
#define TILE_GRID 2048
#define NWIN (N_EDGES / 16)     // 75000 windows, exact (E % 16 == 0)
#define LOG2E 1.44269504f
#define LN2 0.69314718f

typedef _Float16 half8 __attribute__((ext_vector_type(8)));
typedef _Float16 half4 __attribute__((ext_vector_type(4)));
typedef _Float16 half2v __attribute__((ext_vector_type(2)));
typedef float f32x4 __attribute__((ext_vector_type(4)));
typedef int i32x4 __attribute__((ext_vector_type(4)));
union U32H2 { unsigned int u; half2v h; };

// ---------- K1: degree histogram + per-edge rank (single atomic pass) ----------
__global__ __launch_bounds__(256) void degrank_kernel(
    const int* __restrict__ ei, int* __restrict__ deg, int* __restrict__ rank)
{
    int e = blockIdx.x * 256 + threadIdx.x;
    if (e >= N_EDGES) return;
    rank[e] = atomicAdd(&deg[ei[N_EDGES + e]], 1);
}

// ---------- scan ----------
__global__ __launch_bounds__(256) void scan_a_kernel(const int* __restrict__ deg, int* __restrict__ bsums)
{
    __shared__ int sm[256];
    int tid = threadIdx.x;
    int i = blockIdx.x * 256 + tid;
    int v = (i < N_NODES) ? deg[i] : 0;
    sm[tid] = v;
    __syncthreads();
    for (int s = 128; s > 0; s >>= 1) {
        if (tid < s) sm[tid] += sm[tid + s];
        __syncthreads();
    }
    if (tid == 0) bsums[blockIdx.x] = sm[0];
}

// scan_c with fused block-offset reduction (absorbs old scan_b)
__global__ __launch_bounds__(256) void scan_c_kernel(
    const int* __restrict__ deg, const int* __restrict__ bsums,
    int* __restrict__ row_st, float* __restrict__ inv_deg)
{
    __shared__ int sm[256];
    int tid = threadIdx.x;
    // phase 1: this block's exclusive offset = sum of bsums[0..blockIdx-1]
    int acc = 0;
    if (tid < blockIdx.x) acc = bsums[tid];
    int t2 = tid + 256;
    if (t2 < blockIdx.x) acc += bsums[t2];
    sm[tid] = acc;
    __syncthreads();
    for (int s = 128; s > 0; s >>= 1) {
        if (tid < s) sm[tid] += sm[tid + s];
        __syncthreads();
    }
    int boff = sm[0];
    __syncthreads();
    // phase 2: inclusive scan of this block's 256 degrees
    int i = blockIdx.x * 256 + tid;
    int v = (i < N_NODES) ? deg[i] : 0;
    sm[tid] = v;
    __syncthreads();
    for (int off = 1; off < 256; off <<= 1) {
        int t = (tid >= off) ? sm[tid - off] : 0;
        __syncthreads();
        sm[tid] += t;
        __syncthreads();
    }
    if (i <= N_NODES) row_st[i] = boff + sm[tid] - v;  // exclusive
    if (i < N_NODES) inv_deg[i] = (v > 0) ? (1.0f / (float)v) : 0.0f;
}

// ---------- K2a: atomic-free scatter into CSR order ----------
__global__ __launch_bounds__(256) void scatter_perm_kernel(
    const int* __restrict__ ei, const int* __restrict__ row_st,
    const int* __restrict__ rank, int* __restrict__ csr_src, int* __restrict__ csr_dst)
{
    int e = blockIdx.x * 256 + threadIdx.x;
    if (e >= N_EDGES) return;
    int s = ei[e];
    int d = ei[N_EDGES + e];
    int idx = row_st[d] + rank[e];
    csr_src[idx] = s;
    csr_dst[idx] = d;
}

// ---------- K2b (fused): RBF + window metadata in ONE coalesced pass ----------
__global__ __launch_bounds__(256) void edge_post_kernel(
    const int* __restrict__ csr_src, const int* __restrict__ csr_dst,
    const float* __restrict__ pos, const float* __restrict__ inv_deg,
    const float* __restrict__ means, const float* __restrict__ betas,
    unsigned int* __restrict__ ea,
    unsigned char* __restrict__ seg8, int* __restrict__ wnode,
    _Float16* __restrict__ inv_e)
{
    __shared__ int sdst[256];
    int t = blockIdx.x * 256 + threadIdx.x;
    if (t < N_EDGES) {
        int s = csr_src[t];
        int d = csr_dst[t];
        sdst[threadIdx.x] = d;
        inv_e[t] = (_Float16)(inv_deg[d] * LN2);

        float dx = pos[s * 3 + 0] - pos[d * 3 + 0];
        float dy = pos[s * 3 + 1] - pos[d * 3 + 1];
        float dz = pos[s * 3 + 2] - pos[d * 3 + 2];
        float dist = sqrtf(dx * dx + dy * dy + dz * dz + 1e-12f);
        float cut = 0.0f;
        if (dist < 5.0f) cut = 0.5f * (__cosf(dist * 0.6283185307179586f) + 1.0f);
        float ex = __expf(-dist);
        union { _Float16 h[32]; uint4 u[4]; } pk;
#pragma unroll
        for (int k = 0; k < 32; k++) {
            float vk = ex - means[k];
            pk.h[k] = (_Float16)(cut * __expf(-betas[k] * vk * vk));
        }
        uint4* op = (uint4*)(ea + (size_t)t * 16);
        op[0] = pk.u[0];
        op[1] = pk.u[1];
        op[2] = pk.u[2];
        op[3] = pk.u[3];
    }
    __syncthreads();
    if (threadIdx.x < 16) {
        int w0 = blockIdx.x * 16 + threadIdx.x;      // global window id
        if ((size_t)w0 * 16 < N_EDGES) {             // whole windows only (E%16==0)
            int lb = threadIdx.x * 16;
            int gb = w0 * 16;
            int prev = -1, sg = -1;
            for (int k = 0; k < 16; k++) {
                int dd = sdst[lb + k];
                if (dd != prev) { sg++; prev = dd; wnode[gb + sg] = dd; }
                seg8[gb + k] = (unsigned char)sg;
            }
            for (int m = sg + 1; m < 16; m++) wnode[gb + m] = -1;
        }
    }
}

// ---------- K3 (fused): weight cvt/transpose + atom-type pre-layer table ----------
__global__ __launch_bounds__(256) void prep_const_kernel(
    const float* __restrict__ Wf, const float* __restrict__ Ws,
    _Float16* __restrict__ wf16, _Float16* __restrict__ ws16,
    const float* __restrict__ emb, const float* __restrict__ pre_W,
    const float* __restrict__ pre_b, float* __restrict__ T)
{
    int b = blockIdx.x;
    if (b < 160) {
        int i = b * 256 + threadIdx.x;   // NLAYERS*160*64 = 40960 exact
        int l = i / (160 * GC);
        int r = i - l * 160 * GC;
        int k = r >> 6;
        int col = r & 63;
        size_t o = ((size_t)l * GC + col) * 160 + k;
        wf16[o] = (_Float16)(Wf[i] * LOG2E);
        ws16[o] = (_Float16)(Ws[i] * LOG2E);
    } else {
        int a = (b - 160) * 4 + (threadIdx.x >> 6);
        int c = threadIdx.x & 63;
        if (a < NATOM) {
            float acc = pre_b[c];
            for (int k = 0; k < NF; k++) acc = fmaf(emb[a * NF + k], pre_W[k * GC + c], acc);
            T[a * GC + c] = fmaxf(acc, 0.0f);
        }
    }
}

// ---------- shared proj body: P2[node][ch] = {f,s} half2, bias*log2e folded ----------
static __device__ __forceinline__ void proj_mfma16(
    const _Float16* __restrict__ wf, const _Float16* __restrict__ ws,
    const float* __restrict__ bfv, const float* __restrict__ bsv,
    const half8 Bn[2], int cb, int node, unsigned int* __restrict__ P2u)
{
    const int lane = threadIdx.x & 63;
    const int quad = lane >> 4;
    const int r16 = lane & 15;
    f32x4 accf[2], accs[2];
#pragma unroll
    for (int sub = 0; sub < 2; sub++) {
        accf[sub] = (f32x4){0.f, 0.f, 0.f, 0.f};
        accs[sub] = (f32x4){0.f, 0.f, 0.f, 0.f};
    }
#pragma unroll
    for (int kt = 0; kt < 2; kt++) {
#pragma unroll
        for (int sub = 0; sub < 2; sub++) {
            int chan = cb + sub * 16 + r16;
            half8 a = *(const half8*)(wf + (size_t)chan * 160 + kt * 32 + quad * 8);
            half8 b = *(const half8*)(ws + (size_t)chan * 160 + kt * 32 + quad * 8);
            accf[sub] = __builtin_amdgcn_mfma_f32_16x16x32_f16(a, Bn[kt], accf[sub], 0, 0, 0);
            accs[sub] = __builtin_amdgcn_mfma_f32_16x16x32_f16(b, Bn[kt], accs[sub], 0, 0, 0);
        }
    }
#pragma unroll
    for (int sub = 0; sub < 2; sub++) {
        float4 bf4 = *(const float4*)(bfv + cb + sub * 16 + quad * 4);
        float4 bs4 = *(const float4*)(bsv + cb + sub * 16 + quad * 4);
        half8 h = { (_Float16)(accf[sub][0] + bf4.x * LOG2E), (_Float16)(accs[sub][0] + bs4.x * LOG2E),
                    (_Float16)(accf[sub][1] + bf4.y * LOG2E), (_Float16)(accs[sub][1] + bs4.y * LOG2E),
                    (_Float16)(accf[sub][2] + bf4.z * LOG2E), (_Float16)(accs[sub][2] + bs4.z * LOG2E),
                    (_Float16)(accf[sub][3] + bf4.w * LOG2E), (_Float16)(accs[sub][3] + bs4.w * LOG2E) };
        *(half8*)(P2u + (size_t)node * GC + cb + sub * 16 + quad * 4) = h;
    }
}

// ---------- K_initproj: xinit (table broadcast) fused with proj (layer 0) ----------
__global__ __launch_bounds__(256) void initproj_kernel(
    const int* __restrict__ atom_types, const float* __restrict__ T,
    float* __restrict__ x, _Float16* __restrict__ x16,
    const _Float16* __restrict__ wf, const _Float16* __restrict__ ws,
    const float* __restrict__ bfv, const float* __restrict__ bsv,
    unsigned int* __restrict__ P2u)
{
    __shared__ _Float16 lx[32 * 72];
    const int nb = blockIdx.x * 32;

#pragma unroll
    for (int rep = 0; rep < 2; rep++) {
        int g = rep * 256 + threadIdx.x;        // granule within block: 0..511
        int gi = blockIdx.x * 512 + g;          // global float4 granule
        int node = g >> 4;                      // 0..31
        int c4 = (g & 15) * 4;
        int a = atom_types[nb + node];
        float4 v = ((const float4*)T)[a * 16 + (g & 15)];
        ((float4*)x)[gi] = v;
        half4 h = { (_Float16)v.x, (_Float16)v.y, (_Float16)v.z, (_Float16)v.w };
        ((half4*)x16)[gi] = h;
        *(half4*)(lx + node * 72 + c4) = h;
    }
    __syncthreads();

    const int lane = threadIdx.x & 63;
    const int wid = threadIdx.x >> 6;
    const int quad = lane >> 4;
    const int r16 = lane & 15;
    const int cb = (wid & 1) * 32;
    const int tn = (wid >> 1) * 16 + r16;       // node within block's 32
    half8 Bn[2];
    Bn[0] = *(const half8*)(lx + tn * 72 + quad * 8);
    Bn[1] = *(const half8*)(lx + tn * 72 + 32 + quad * 8);
    proj_mfma16(wf, ws, bfv, bsv, Bn, cb, nb + tn, P2u);
}

// ---------- K_bnproj: BN apply (layer l) fused with proj (layer l+1) ----------
__global__ __launch_bounds__(256) void bnproj_kernel(
    const float* __restrict__ xn, const float* __restrict__ stats,
    const float* __restrict__ gamma, const float* __restrict__ beta,
    float* __restrict__ xout, _Float16* __restrict__ x16,
    const _Float16* __restrict__ wf, const _Float16* __restrict__ ws,  // next layer
    const float* __restrict__ bfv, const float* __restrict__ bsv,      // next layer
    unsigned int* __restrict__ P2u)
{
    __shared__ _Float16 lx[32 * 72];   // 72-half row pad -> free 2-way LDS banks
    const int nb = blockIdx.x * 32;
    const float invN = 1.0f / (float)N_NODES;

#pragma unroll
    for (int rep = 0; rep < 2; rep++) {
        int g = rep * 256 + threadIdx.x;        // granule within block: 0..511
        int gi = blockIdx.x * 512 + g;          // global float4 granule
        int node = g >> 4;                      // 0..31
        int c4 = (g & 15) * 4;
        float4 v = ((const float4*)xn)[gi];
        float vv[4] = {v.x, v.y, v.z, v.w};
        float o[4];
#pragma unroll
        for (int t = 0; t < 4; t++) {
            int c = c4 + t;
            float mu = stats[c] * invN;
            float var = stats[64 + c] * invN - mu * mu;
            float sc = gamma[c] * rsqrtf(var + BN_EPS);
            o[t] = (vv[t] - mu) * sc + beta[c];
        }
        ((float4*)xout)[gi] = make_float4(o[0], o[1], o[2], o[3]);
        half4 h = { (_Float16)o[0], (_Float16)o[1], (_Float16)o[2], (_Float16)o[3] };
        ((half4*)x16)[gi] = h;
        *(half4*)(lx + node * 72 + c4) = h;
    }
    __syncthreads();

    const int lane = threadIdx.x & 63;
    const int wid = threadIdx.x >> 6;
    const int quad = lane >> 4;
    const int r16 = lane & 15;
    const int cb = (wid & 1) * 32;
    const int tn = (wid >> 1) * 16 + r16;       // node within block's 32
    half8 Bn[2];
    Bn[0] = *(const half8*)(lx + tn * 72 + quad * 8);
    Bn[1] = *(const half8*)(lx + tn * 72 + 32 + quad * 8);
    proj_mfma16(wf, ws, bfv, bsv, Bn, cb, nb + tn, P2u);
}

// ---------- window compute body ----------
// MFMA into zero acc; P2[dst] (dst-proj + bias, log2e domain) added AFTER the MFMA
// block (commutes), so pv/meta loads are issued at entry and consumed 150-250cy later.
static __device__ __forceinline__ void compute_win(
    half8 S0, half8 S1, half8 E, i32x4 d4, int moff,
    const half8 (&WGF)[3][2], const half8 (&WGS)[3][2],
    int r16, int quad, int cb,
    const unsigned char* __restrict__ seg8, const int* __restrict__ wnode,
    const _Float16* __restrict__ inv_e, const unsigned int* __restrict__ P2u,
    float* __restrict__ x)
{
    // issue gathers/meta now; consumers are after the MFMA block
    unsigned int pv0, pv1, pv2, pv3, pv4, pv5, pv6, pv7;
    {
        const unsigned int* p0 = P2u + (size_t)d4[0] * GC + cb + r16;
        const unsigned int* p1 = P2u + (size_t)d4[1] * GC + cb + r16;
        const unsigned int* p2 = P2u + (size_t)d4[2] * GC + cb + r16;
        const unsigned int* p3 = P2u + (size_t)d4[3] * GC + cb + r16;
        pv0 = p0[0];  pv4 = p0[16];
        pv1 = p1[0];  pv5 = p1[16];
        pv2 = p2[0];  pv6 = p2[16];
        pv3 = p3[0];  pv7 = p3[16];
    }
    unsigned int segq = __builtin_nontemporal_load((const unsigned int*)(seg8 + moff + quad * 4));
    i32x4 wn4 = __builtin_nontemporal_load((const i32x4*)(wnode + moff + quad * 4));
    half4 inv4 = __builtin_nontemporal_load((const half4*)(inv_e + moff + quad * 4));

    const f32x4 zf = (f32x4){0.0f, 0.0f, 0.0f, 0.0f};
    f32x4 accf[2], accs[2];
    __builtin_amdgcn_s_setprio(1);
#pragma unroll
    for (int ctl = 0; ctl < 2; ctl++) {
        accf[ctl] = __builtin_amdgcn_mfma_f32_16x16x32_f16(S0, WGF[0][ctl], zf, 0, 0, 0);
        accs[ctl] = __builtin_amdgcn_mfma_f32_16x16x32_f16(S0, WGS[0][ctl], zf, 0, 0, 0);
        accf[ctl] = __builtin_amdgcn_mfma_f32_16x16x32_f16(S1, WGF[1][ctl], accf[ctl], 0, 0, 0);
        accs[ctl] = __builtin_amdgcn_mfma_f32_16x16x32_f16(S1, WGS[1][ctl], accs[ctl], 0, 0, 0);
        accf[ctl] = __builtin_amdgcn_mfma_f32_16x16x32_f16(E,  WGF[2][ctl], accf[ctl], 0, 0, 0);
        accs[ctl] = __builtin_amdgcn_mfma_f32_16x16x32_f16(E,  WGS[2][ctl], accs[ctl], 0, 0, 0);
    }
    __builtin_amdgcn_s_setprio(0);

    // add P2 (dst proj + bias), then activation in log2 domain:
    //   sigmoid = rcp(1 + 2^-F')   softplus = ln2*log2(1+2^S')  (ln2 folded into inv_e)
    unsigned int pvv[8] = {pv0, pv1, pv2, pv3, pv4, pv5, pv6, pv7};
    half4 msgh[2];
#pragma unroll
    for (int ctl = 0; ctl < 2; ctl++) {
#pragma unroll
        for (int rr = 0; rr < 4; rr++) {
            U32H2 t; t.u = pvv[ctl * 4 + rr];
            float af = accf[ctl][rr] + (float)t.h.x;
            float as = accs[ctl][rr] + (float)t.h.y;
            float sg = __builtin_amdgcn_rcpf(1.0f + __builtin_amdgcn_exp2f(-af));
            float sp = __builtin_amdgcn_logf(1.0f + __builtin_amdgcn_exp2f(as));
            msgh[ctl][rr] = (_Float16)(sg * sp);
        }
    }
    // segment mask fragment: A[m=r16][k=quad*4+j] = (seg(k)==m) ? inv_deg(k)*ln2 : 0
    half4 am;
#pragma unroll
    for (int j = 0; j < 4; j++) {
        int sj = (segq >> (8 * j)) & 0xff;
        am[j] = (sj == r16) ? inv4[j] : (_Float16)0.0f;
    }
#pragma unroll
    for (int ctl = 0; ctl < 2; ctl++) {
        f32x4 red = __builtin_amdgcn_mfma_f32_16x16x16f16(am, msgh[ctl], zf, 0, 0, 0);
#pragma unroll
        for (int rr = 0; rr < 4; rr++) {
            int nd = wn4[rr];
            if (nd >= 0) atomicAdd(&x[(size_t)nd * GC + cb + ctl * 16 + r16], red[rr]);
        }
    }
}

// refill one frag set from window WW_ using prefetched SRC_ (ea is streamed: nt load)
#define LOADSET(S0_, S1_, EE_, SRC_, WW_)                                            \
    S0_ = *(const half8*)(x16 + (size_t)(SRC_) * GC + quad * 8);                     \
    S1_ = *(const half8*)(x16 + (size_t)(SRC_) * GC + 32 + quad * 8);                \
    EE_ = __builtin_nontemporal_load((const half8*)(ea + ((size_t)(WW_) * 16 + r16) * RBF + quad * 8));

// ---------- K5: window MFMA CGConv layer (3-deep data pipeline) ----------
__global__ __launch_bounds__(256, 3) void win_mfma_kernel(
    const _Float16* __restrict__ x16, const _Float16* __restrict__ ea,
    const int* __restrict__ csr_src, const int* __restrict__ csr_dst,
    const unsigned char* __restrict__ seg8, const int* __restrict__ wnode,
    const _Float16* __restrict__ inv_e, const unsigned int* __restrict__ P2u,
    const _Float16* __restrict__ wf16, const _Float16* __restrict__ ws16, // layer base [64][160]
    float* __restrict__ x)
{
    const int lane = threadIdx.x & 63;
    const int wid = __builtin_amdgcn_readfirstlane(threadIdx.x >> 6);
    const int quad = lane >> 4;
    const int r16 = lane & 15;
    const int wgid = blockIdx.x * 4 + wid;
    const int cb = (wgid & 1) * 32;
    int w = wgid >> 1;
    const int NSEQ = TILE_GRID * 2;

    // resident weight fragments: rows 64..159 (src + rbf), 3 K-tiles x 2 ctl halves
    half8 WGF[3][2], WGS[3][2];
#pragma unroll
    for (int ctl = 0; ctl < 2; ctl++) {
        const _Float16* wfp = wf16 + (size_t)(cb + ctl * 16 + r16) * 160 + 64 + quad * 8;
        const _Float16* wsp = ws16 + (size_t)(cb + ctl * 16 + r16) * 160 + 64 + quad * 8;
#pragma unroll
        for (int kt = 0; kt < 3; kt++) {
            WGF[kt][ctl] = *(const half8*)(wfp + kt * 32);
            WGS[kt][ctl] = *(const half8*)(wsp + kt * 32);
        }
    }

    // ---- prologue: sets A/B/C = windows w, w+N, w+2N; addr stage D = w+3N ----
    half8 AS0, AS1, AE, BS0, BS1, BE, CS0, CS1, CE;
    i32x4 d4A, d4B, d4C;
    int moffA, moffB, moffC;
    {
        int s_ = __builtin_nontemporal_load(csr_src + w * 16 + r16);
        d4A = __builtin_nontemporal_load((const i32x4*)(csr_dst + w * 16 + quad * 4));
        LOADSET(AS0, AS1, AE, s_, w);
        moffA = w * 16;
    }
    {
        int wB = w + NSEQ; if (wB >= NWIN) wB = NWIN - 1;
        int s_ = __builtin_nontemporal_load(csr_src + wB * 16 + r16);
        d4B = __builtin_nontemporal_load((const i32x4*)(csr_dst + wB * 16 + quad * 4));
        LOADSET(BS0, BS1, BE, s_, wB);
        moffB = wB * 16;
    }
    {
        int wCx = w + 2 * NSEQ; if (wCx >= NWIN) wCx = NWIN - 1;
        int s_ = __builtin_nontemporal_load(csr_src + wCx * 16 + r16);
        d4C = __builtin_nontemporal_load((const i32x4*)(csr_dst + wCx * 16 + quad * 4));
        LOADSET(CS0, CS1, CE, s_, wCx);
        moffC = wCx * 16;
    }
    int wD = w + 3 * NSEQ; if (wD >= NWIN) wD = NWIN - 1;
    int sD = __builtin_nontemporal_load(csr_src + wD * 16 + r16);
    i32x4 d4D = __builtin_nontemporal_load((const i32x4*)(csr_dst + wD * 16 + quad * 4));

    while (true) {
        compute_win(AS0, AS1, AE, d4A, moffA,
                    WGF, WGS, r16, quad, cb, seg8, wnode, inv_e, P2u, x);
        LOADSET(AS0, AS1, AE, sD, wD);
        d4A = d4D; moffA = wD * 16;
        wD += NSEQ; if (wD >= NWIN) wD = NWIN - 1;
        sD = __builtin_nontemporal_load(csr_src + wD * 16 + r16);
        d4D = __builtin_nontemporal_load((const i32x4*)(csr_dst + wD * 16 + quad * 4));
        w += NSEQ;
        if (w >= NWIN) break;

        compute_win(BS0, BS1, BE, d4B, moffB,
                    WGF, WGS, r16, quad, cb, seg8, wnode, inv_e, P2u, x);
        LOADSET(BS0, BS1, BE, sD, wD);
        d4B = d4D; moffB = wD * 16;
        wD += NSEQ; if (wD >= NWIN) wD = NWIN - 1;
        sD = __builtin_nontemporal_load(csr_src + wD * 16 + r16);
        d4D = __builtin_nontemporal_load((const i32x4*)(csr_dst + wD * 16 + quad * 4));
        w += NSEQ;
        if (w >= NWIN) break;

        compute_win(CS0, CS1, CE, d4C, moffC,
                    WGF, WGS, r16, quad, cb, seg8, wnode, inv_e, P2u, x);
        LOADSET(CS0, CS1, CE, sD, wD);
        d4C = d4D; moffC = wD * 16;
        wD += NSEQ; if (wD >= NWIN) wD = NWIN - 1;
        sD = __builtin_nontemporal_load(csr_src + wD * 16 + r16);
        d4D = __builtin_nontemporal_load((const i32x4*)(csr_dst + wD * 16 + quad * 4));
        w += NSEQ;
        if (w >= NWIN) break;
    }
}

// ---------- K6: BN stats ----------
__global__ __launch_bounds__(256) void stats_kernel(const float* __restrict__ x, float* __restrict__ stats)
{
    const int lane = threadIdx.x & 63;
    const int wid = threadIdx.x >> 6;
    int w = blockIdx.x * 4 + wid;
    float s1 = 0.0f, s2 = 0.0f;
    for (int n = w; n < N_NODES; n += 2048) {
        float v = x[(size_t)n * GC + lane];
        s1 += v;
        s2 = fmaf(v, v, s2);
    }
    __shared__ float rs1[4][64];
    __shared__ float rs2[4][64];
    rs1[wid][lane] = s1;
    rs2[wid][lane] = s2;
    __syncthreads();
    if (threadIdx.x < 64) {
        atomicAdd(&stats[lane], rs1[0][lane] + rs1[1][lane] + rs1[2][lane] + rs1[3][lane]);
    } else if (threadIdx.x < 128) {
        int c = threadIdx.x & 63;
        atomicAdd(&stats[64 + c], rs2[0][c] + rs2[1][c] + rs2[2][c] + rs2[3][c]);
    }
}

// ---------- K7: final batchnorm apply (layer 3 -> d_out) ----------
__global__ __launch_bounds__(256) void bn_kernel(
    const float* __restrict__ xn, const float* __restrict__ stats,
    const float* __restrict__ gamma, const float* __restrict__ beta,
    float* __restrict__ out)
{
    int i = blockIdx.x * 256 + threadIdx.x;
    int c4 = (i & 15) * 4;
    float4 v = ((const float4*)xn)[i];
    float vv[4] = {v.x, v.y, v.z, v.w};
    float o[4];
    const float invN = 1.0f / (float)N_NODES;
#pragma unroll
    for (int t = 0; t < 4; t++) {
        int c = c4 + t;
        float mu = stats[c] * invN;
        float var = stats[64 + c] * invN - mu * mu;
        float sc = gamma[c] * rsqrtf(var + BN_EPS);
        o[t] = (vv[t] - mu) * sc + beta[c];
    }
    ((float4*)out)[i] = make_float4(o[0], o[1], o[2], o[3]);
}

extern "C" void kernel_launch(void* const* d_in, const int* in_sizes, int n_in,
                              void* d_out, int out_size, void* d_ws, size_t ws_size,
                              hipStream_t stream)
{
    const int* atom_types = (const int*)d_in[0];
    const float* pos = (const float*)d_in[1];
    const int* edge_index = (const int*)d_in[2];
    const float* emb = (const float*)d_in[3];
    const float* pre_W = (const float*)d_in[4];
    const float* pre_b = (const float*)d_in[5];
    const float* Wf = (const float*)d_in[6];
    const float* bf = (const float*)d_in[7];
    const float* Ws = (const float*)d_in[8];
    const float* bs = (const float*)d_in[9];
    const float* gamma = (const float*)d_in[10];
    const float* beta = (const float*)d_in[11];
    const float* means = (const float*)d_in[12];
    const float* betas = (const float*)d_in[13];

    char* base = (char*)d_ws;
    char* p = base;
    auto alloc = [&](size_t bytes) -> char* {
        char* r = p;
        p += (bytes + 255) & ~(size_t)255;
        return r;
    };
    unsigned int* ea = (unsigned int*)alloc((size_t)N_EDGES * RBF * 2);    // 76.8 MB fp16
    float* x = (float*)alloc((size_t)N_NODES * GC * 4);                    // 25.6 MB
    _Float16* x16 = (_Float16*)alloc((size_t)N_NODES * GC * 2);            // 12.8 MB
    unsigned int* P2u = (unsigned int*)alloc((size_t)N_NODES * GC * 4);    // 25.6 MB {f,s} half2
    int* csr_src = (int*)alloc((size_t)N_EDGES * 4);                       // 4.8 MB
    int* csr_dst = (int*)alloc((size_t)N_EDGES * 4);                       // 4.8 MB
    int* rank = (int*)alloc((size_t)N_EDGES * 4);                          // 4.8 MB
    int* wnode = (int*)alloc((size_t)N_EDGES * 4);                         // 4.8 MB
    unsigned char* seg8 = (unsigned char*)alloc((size_t)N_EDGES);          // 1.2 MB
    _Float16* inv_e = (_Float16*)alloc((size_t)N_EDGES * 2);               // 2.4 MB
    _Float16* wf16 = (_Float16*)alloc((size_t)NLAYERS * GC * 160 * 2);     // 80 KB
    _Float16* ws16 = (_Float16*)alloc((size_t)NLAYERS * GC * 160 * 2);     // 80 KB
    int* row_st = (int*)alloc((size_t)(N_NODES + 1) * 4);
    float* inv_deg = (float*)alloc((size_t)N_NODES * 4);
    float* T = (float*)alloc((size_t)NATOM * GC * 4);
    int* bsums = (int*)alloc(512 * 4);
    const size_t ZR_INTS = (size_t)N_NODES + 128 * NLAYERS + 64;
    char* zr = alloc(ZR_INTS * 4);
    int* deg = (int*)zr;
    float* stats = (float*)(deg + N_NODES);

    if ((size_t)(p - base) > ws_size) return;  // diagnostic bail

    (void)hipMemsetAsync(zr, 0, ZR_INTS * 4, stream);

    const int EG = (N_EDGES + 255) / 256;
    degrank_kernel<<<EG, 256, 0, stream>>>(edge_index, deg, rank);
    scan_a_kernel<<<391, 256, 0, stream>>>(deg, bsums);
    scan_c_kernel<<<391, 256, 0, stream>>>(deg, bsums, row_st, inv_deg);
    scatter_perm_kernel<<<EG, 256, 0, stream>>>(edge_index, row_st, rank, csr_src, csr_dst);
    edge_post_kernel<<<EG, 256, 0, stream>>>(csr_src, csr_dst, pos, inv_deg, means, betas,
                                             ea, seg8, wnode, inv_e);
    prep_const_kernel<<<185, 256, 0, stream>>>(Wf, Ws, wf16, ws16, emb, pre_W, pre_b, T);
    initproj_kernel<<<N_NODES / 32, 256, 0, stream>>>(atom_types, T, x, x16,
                                                      wf16, ws16, bf, bs, P2u);

    for (int l = 0; l < NLAYERS; l++) {
        win_mfma_kernel<<<TILE_GRID, 256, 0, stream>>>(
            x16, (const _Float16*)ea, csr_src, csr_dst, seg8, wnode, inv_e, P2u,
            wf16 + (size_t)l * GC * 160, ws16 + (size_t)l * GC * 160, x);
        stats_kernel<<<512, 256, 0, stream>>>(x, stats + l * 128);
        if (l < NLAYERS - 1) {
            bnproj_kernel<<<N_NODES / 32, 256, 0, stream>>>(
                x, stats + l * 128, gamma + l * GC, beta + l * GC, x, x16,
                wf16 + (size_t)(l + 1) * GC * 160, ws16 + (size_t)(l + 1) * GC * 160,
                bf + (l + 1) * GC, bs + (l + 1) * GC, P2u);
        } else {
            bn_kernel<<<N_NODES * 16 / 256, 256, 0, stream>>>(
                x, stats + l * 128, gamma + l * GC, beta + l * GC, (float*)d_out);
        }
    }
}

// Round 10
// 762.338 us; speedup vs baseline: 1.0730x; 1.0730x over previous
//
#include <hip/hip_runtime.h>
#include <math.h>

#define N_NODES 100000
#define N_EDGES 1200000
#define GC 64
#define RBF 32
#define NLAYERS 4
#define NF 92
#define NATOM 100
#define BN_EPS 1e-5f
#define TILE_GRID 2048
#define NWIN (N_EDGES / 16)     // 75000 windows, exact (E % 16 == 0)
#define LOG2E 1.44269504f
#define LN2 0.69314718f

typedef _Float16 half8 __attribute__((ext_vector_type(8)));
typedef _Float16 half4 __attribute__((ext_vector_type(4)));
typedef _Float16 half2v __attribute__((ext_vector_type(2)));
typedef float f32x4 __attribute__((ext_vector_type(4)));
typedef int i32x4 __attribute__((ext_vector_type(4)));
union U32H2 { unsigned int u; half2v h; };

// ---------- K1: degree histogram + per-edge rank (single atomic pass) ----------
__global__ __launch_bounds__(256) void degrank_kernel(
    const int* __restrict__ ei, int* __restrict__ deg, int* __restrict__ rank)
{
    int e = blockIdx.x * 256 + threadIdx.x;
    if (e >= N_EDGES) return;
    rank[e] = atomicAdd(&deg[ei[N_EDGES + e]], 1);
}

// ---------- scan ----------
__global__ __launch_bounds__(256) void scan_a_kernel(const int* __restrict__ deg, int* __restrict__ bsums)
{
    __shared__ int sm[256];
    int tid = threadIdx.x;
    int i = blockIdx.x * 256 + tid;
    int v = (i < N_NODES) ? deg[i] : 0;
    sm[tid] = v;
    __syncthreads();
    for (int s = 128; s > 0; s >>= 1) {
        if (tid < s) sm[tid] += sm[tid + s];
        __syncthreads();
    }
    if (tid == 0) bsums[blockIdx.x] = sm[0];
}

// scan_c with fused block-offset reduction (absorbs old scan_b)
__global__ __launch_bounds__(256) void scan_c_kernel(
    const int* __restrict__ deg, const int* __restrict__ bsums,
    int* __restrict__ row_st, float* __restrict__ inv_deg)
{
    __shared__ int sm[256];
    int tid = threadIdx.x;
    // phase 1: this block's exclusive offset = sum of bsums[0..blockIdx-1]
    int acc = 0;
    if (tid < blockIdx.x) acc = bsums[tid];
    int t2 = tid + 256;
    if (t2 < blockIdx.x) acc += bsums[t2];
    sm[tid] = acc;
    __syncthreads();
    for (int s = 128; s > 0; s >>= 1) {
        if (tid < s) sm[tid] += sm[tid + s];
        __syncthreads();
    }
    int boff = sm[0];
    __syncthreads();
    // phase 2: inclusive scan of this block's 256 degrees
    int i = blockIdx.x * 256 + tid;
    int v = (i < N_NODES) ? deg[i] : 0;
    sm[tid] = v;
    __syncthreads();
    for (int off = 1; off < 256; off <<= 1) {
        int t = (tid >= off) ? sm[tid - off] : 0;
        __syncthreads();
        sm[tid] += t;
        __syncthreads();
    }
    if (i <= N_NODES) row_st[i] = boff + sm[tid] - v;  // exclusive
    if (i < N_NODES) inv_deg[i] = (v > 0) ? (1.0f / (float)v) : 0.0f;
}

// ---------- K2a: atomic-free scatter into CSR order ----------
__global__ __launch_bounds__(256) void scatter_perm_kernel(
    const int* __restrict__ ei, const int* __restrict__ row_st,
    const int* __restrict__ rank, int* __restrict__ csr_src, int* __restrict__ csr_dst)
{
    int e = blockIdx.x * 256 + threadIdx.x;
    if (e >= N_EDGES) return;
    int s = ei[e];
    int d = ei[N_EDGES + e];
    int idx = row_st[d] + rank[e];
    csr_src[idx] = s;
    csr_dst[idx] = d;
}

// ---------- K2b (fused): RBF + window metadata in ONE coalesced pass ----------
__global__ __launch_bounds__(256) void edge_post_kernel(
    const int* __restrict__ csr_src, const int* __restrict__ csr_dst,
    const float* __restrict__ pos, const float* __restrict__ inv_deg,
    const float* __restrict__ means, const float* __restrict__ betas,
    unsigned int* __restrict__ ea,
    unsigned char* __restrict__ seg8, int* __restrict__ wnode,
    _Float16* __restrict__ inv_e)
{
    __shared__ int sdst[256];
    int t = blockIdx.x * 256 + threadIdx.x;
    if (t < N_EDGES) {
        int s = csr_src[t];
        int d = csr_dst[t];
        sdst[threadIdx.x] = d;
        inv_e[t] = (_Float16)(inv_deg[d] * LN2);

        float dx = pos[s * 3 + 0] - pos[d * 3 + 0];
        float dy = pos[s * 3 + 1] - pos[d * 3 + 1];
        float dz = pos[s * 3 + 2] - pos[d * 3 + 2];
        float dist = sqrtf(dx * dx + dy * dy + dz * dz + 1e-12f);
        float cut = 0.0f;
        if (dist < 5.0f) cut = 0.5f * (__cosf(dist * 0.6283185307179586f) + 1.0f);
        float ex = __expf(-dist);
        union { _Float16 h[32]; uint4 u[4]; } pk;
#pragma unroll
        for (int k = 0; k < 32; k++) {
            float vk = ex - means[k];
            pk.h[k] = (_Float16)(cut * __expf(-betas[k] * vk * vk));
        }
        uint4* op = (uint4*)(ea + (size_t)t * 16);
        op[0] = pk.u[0];
        op[1] = pk.u[1];
        op[2] = pk.u[2];
        op[3] = pk.u[3];
    }
    __syncthreads();
    if (threadIdx.x < 16) {
        int w0 = blockIdx.x * 16 + threadIdx.x;      // global window id
        if ((size_t)w0 * 16 < N_EDGES) {             // whole windows only (E%16==0)
            int lb = threadIdx.x * 16;
            int gb = w0 * 16;
            int prev = -1, sg = -1;
            for (int k = 0; k < 16; k++) {
                int dd = sdst[lb + k];
                if (dd != prev) { sg++; prev = dd; wnode[gb + sg] = dd; }
                seg8[gb + k] = (unsigned char)sg;
            }
            for (int m = sg + 1; m < 16; m++) wnode[gb + m] = -1;
        }
    }
}

// ---------- K3 (fused): weight cvt/transpose + atom-type pre-layer table ----------
__global__ __launch_bounds__(256) void prep_const_kernel(
    const float* __restrict__ Wf, const float* __restrict__ Ws,
    _Float16* __restrict__ wf16, _Float16* __restrict__ ws16,
    const float* __restrict__ emb, const float* __restrict__ pre_W,
    const float* __restrict__ pre_b, float* __restrict__ T)
{
    int b = blockIdx.x;
    if (b < 160) {
        int i = b * 256 + threadIdx.x;   // NLAYERS*160*64 = 40960 exact
        int l = i / (160 * GC);
        int r = i - l * 160 * GC;
        int k = r >> 6;
        int col = r & 63;
        size_t o = ((size_t)l * GC + col) * 160 + k;
        wf16[o] = (_Float16)(Wf[i] * LOG2E);
        ws16[o] = (_Float16)(Ws[i] * LOG2E);
    } else {
        int a = (b - 160) * 4 + (threadIdx.x >> 6);
        int c = threadIdx.x & 63;
        if (a < NATOM) {
            float acc = pre_b[c];
            for (int k = 0; k < NF; k++) acc = fmaf(emb[a * NF + k], pre_W[k * GC + c], acc);
            T[a * GC + c] = fmaxf(acc, 0.0f);
        }
    }
}

// ---------- shared proj body: P2[node][ch] = {f,s} half2, bias*log2e folded ----------
static __device__ __forceinline__ void proj_mfma16(
    const _Float16* __restrict__ wf, const _Float16* __restrict__ ws,
    const float* __restrict__ bfv, const float* __restrict__ bsv,
    const half8 Bn[2], int cb, int node, unsigned int* __restrict__ P2u)
{
    const int lane = threadIdx.x & 63;
    const int quad = lane >> 4;
    const int r16 = lane & 15;
    f32x4 accf[2], accs[2];
#pragma unroll
    for (int sub = 0; sub < 2; sub++) {
        accf[sub] = (f32x4){0.f, 0.f, 0.f, 0.f};
        accs[sub] = (f32x4){0.f, 0.f, 0.f, 0.f};
    }
#pragma unroll
    for (int kt = 0; kt < 2; kt++) {
#pragma unroll
        for (int sub = 0; sub < 2; sub++) {
            int chan = cb + sub * 16 + r16;
            half8 a = *(const half8*)(wf + (size_t)chan * 160 + kt * 32 + quad * 8);
            half8 b = *(const half8*)(ws + (size_t)chan * 160 + kt * 32 + quad * 8);
            accf[sub] = __builtin_amdgcn_mfma_f32_16x16x32_f16(a, Bn[kt], accf[sub], 0, 0, 0);
            accs[sub] = __builtin_amdgcn_mfma_f32_16x16x32_f16(b, Bn[kt], accs[sub], 0, 0, 0);
        }
    }
#pragma unroll
    for (int sub = 0; sub < 2; sub++) {
        float4 bf4 = *(const float4*)(bfv + cb + sub * 16 + quad * 4);
        float4 bs4 = *(const float4*)(bsv + cb + sub * 16 + quad * 4);
        half8 h = { (_Float16)(accf[sub][0] + bf4.x * LOG2E), (_Float16)(accs[sub][0] + bs4.x * LOG2E),
                    (_Float16)(accf[sub][1] + bf4.y * LOG2E), (_Float16)(accs[sub][1] + bs4.y * LOG2E),
                    (_Float16)(accf[sub][2] + bf4.z * LOG2E), (_Float16)(accs[sub][2] + bs4.z * LOG2E),
                    (_Float16)(accf[sub][3] + bf4.w * LOG2E), (_Float16)(accs[sub][3] + bs4.w * LOG2E) };
        *(half8*)(P2u + (size_t)node * GC + cb + sub * 16 + quad * 4) = h;
    }
}

// ---------- K_initproj: xinit (table broadcast) fused with proj (layer 0) ----------
__global__ __launch_bounds__(256) void initproj_kernel(
    const int* __restrict__ atom_types, const float* __restrict__ T,
    float* __restrict__ x, _Float16* __restrict__ x16,
    const _Float16* __restrict__ wf, const _Float16* __restrict__ ws,
    const float* __restrict__ bfv, const float* __restrict__ bsv,
    unsigned int* __restrict__ P2u)
{
    __shared__ _Float16 lx[32 * 72];
    const int nb = blockIdx.x * 32;

#pragma unroll
    for (int rep = 0; rep < 2; rep++) {
        int g = rep * 256 + threadIdx.x;        // granule within block: 0..511
        int gi = blockIdx.x * 512 + g;          // global float4 granule
        int node = g >> 4;                      // 0..31
        int c4 = (g & 15) * 4;
        int a = atom_types[nb + node];
        float4 v = ((const float4*)T)[a * 16 + (g & 15)];
        ((float4*)x)[gi] = v;
        half4 h = { (_Float16)v.x, (_Float16)v.y, (_Float16)v.z, (_Float16)v.w };
        ((half4*)x16)[gi] = h;
        *(half4*)(lx + node * 72 + c4) = h;
    }
    __syncthreads();

    const int lane = threadIdx.x & 63;
    const int wid = threadIdx.x >> 6;
    const int quad = lane >> 4;
    const int r16 = lane & 15;
    const int cb = (wid & 1) * 32;
    const int tn = (wid >> 1) * 16 + r16;       // node within block's 32
    half8 Bn[2];
    Bn[0] = *(const half8*)(lx + tn * 72 + quad * 8);
    Bn[1] = *(const half8*)(lx + tn * 72 + 32 + quad * 8);
    proj_mfma16(wf, ws, bfv, bsv, Bn, cb, nb + tn, P2u);
}

// ---------- K_bnproj: BN apply (layer l) fused with proj (layer l+1) ----------
__global__ __launch_bounds__(256) void bnproj_kernel(
    const float* __restrict__ xn, const float* __restrict__ stats,
    const float* __restrict__ gamma, const float* __restrict__ beta,
    float* __restrict__ xout, _Float16* __restrict__ x16,
    const _Float16* __restrict__ wf, const _Float16* __restrict__ ws,  // next layer
    const float* __restrict__ bfv, const float* __restrict__ bsv,      // next layer
    unsigned int* __restrict__ P2u)
{
    __shared__ _Float16 lx[32 * 72];   // 72-half row pad -> free 2-way LDS banks
    const int nb = blockIdx.x * 32;
    const float invN = 1.0f / (float)N_NODES;

#pragma unroll
    for (int rep = 0; rep < 2; rep++) {
        int g = rep * 256 + threadIdx.x;        // granule within block: 0..511
        int gi = blockIdx.x * 512 + g;          // global float4 granule
        int node = g >> 4;                      // 0..31
        int c4 = (g & 15) * 4;
        float4 v = ((const float4*)xn)[gi];
        float vv[4] = {v.x, v.y, v.z, v.w};
        float o[4];
#pragma unroll
        for (int t = 0; t < 4; t++) {
            int c = c4 + t;
            float mu = stats[c] * invN;
            float var = stats[64 + c] * invN - mu * mu;
            float sc = gamma[c] * rsqrtf(var + BN_EPS);
            o[t] = (vv[t] - mu) * sc + beta[c];
        }
        ((float4*)xout)[gi] = make_float4(o[0], o[1], o[2], o[3]);
        half4 h = { (_Float16)o[0], (_Float16)o[1], (_Float16)o[2], (_Float16)o[3] };
        ((half4*)x16)[gi] = h;
        *(half4*)(lx + node * 72 + c4) = h;
    }
    __syncthreads();

    const int lane = threadIdx.x & 63;
    const int wid = threadIdx.x >> 6;
    const int quad = lane >> 4;
    const int r16 = lane & 15;
    const int cb = (wid & 1) * 32;
    const int tn = (wid >> 1) * 16 + r16;       // node within block's 32
    half8 Bn[2];
    Bn[0] = *(const half8*)(lx + tn * 72 + quad * 8);
    Bn[1] = *(const half8*)(lx + tn * 72 + 32 + quad * 8);
    proj_mfma16(wf, ws, bfv, bsv, Bn, cb, nb + tn, P2u);
}

// ---------- window compute body ----------
// MFMA into zero acc; P2[dst] (dst-proj + bias, log2e domain) added AFTER the MFMA
// block (commutes), so pv/meta loads are issued at entry and consumed 150-250cy later.
static __device__ __forceinline__ void compute_win(
    half8 S0, half8 S1, half8 E, i32x4 d4, int moff,
    const half8 (&WGF)[3][2], const half8 (&WGS)[3][2],
    int r16, int quad, int cb,
    const unsigned char* __restrict__ seg8, const int* __restrict__ wnode,
    const _Float16* __restrict__ inv_e, const unsigned int* __restrict__ P2u,
    float* __restrict__ x)
{
    // issue gathers/meta now; consumers are after the MFMA block
    unsigned int pv0, pv1, pv2, pv3, pv4, pv5, pv6, pv7;
    {
        const unsigned int* p0 = P2u + (size_t)d4[0] * GC + cb + r16;
        const unsigned int* p1 = P2u + (size_t)d4[1] * GC + cb + r16;
        const unsigned int* p2 = P2u + (size_t)d4[2] * GC + cb + r16;
        const unsigned int* p3 = P2u + (size_t)d4[3] * GC + cb + r16;
        pv0 = p0[0];  pv4 = p0[16];
        pv1 = p1[0];  pv5 = p1[16];
        pv2 = p2[0];  pv6 = p2[16];
        pv3 = p3[0];  pv7 = p3[16];
    }
    unsigned int segq = *(const unsigned int*)(seg8 + moff + quad * 4);
    i32x4 wn4 = *(const i32x4*)(wnode + moff + quad * 4);
    half4 inv4 = *(const half4*)(inv_e + moff + quad * 4);

    const f32x4 zf = (f32x4){0.0f, 0.0f, 0.0f, 0.0f};
    f32x4 accf[2], accs[2];
    __builtin_amdgcn_s_setprio(1);
#pragma unroll
    for (int ctl = 0; ctl < 2; ctl++) {
        accf[ctl] = __builtin_amdgcn_mfma_f32_16x16x32_f16(S0, WGF[0][ctl], zf, 0, 0, 0);
        accs[ctl] = __builtin_amdgcn_mfma_f32_16x16x32_f16(S0, WGS[0][ctl], zf, 0, 0, 0);
        accf[ctl] = __builtin_amdgcn_mfma_f32_16x16x32_f16(S1, WGF[1][ctl], accf[ctl], 0, 0, 0);
        accs[ctl] = __builtin_amdgcn_mfma_f32_16x16x32_f16(S1, WGS[1][ctl], accs[ctl], 0, 0, 0);
        accf[ctl] = __builtin_amdgcn_mfma_f32_16x16x32_f16(E,  WGF[2][ctl], accf[ctl], 0, 0, 0);
        accs[ctl] = __builtin_amdgcn_mfma_f32_16x16x32_f16(E,  WGS[2][ctl], accs[ctl], 0, 0, 0);
    }
    __builtin_amdgcn_s_setprio(0);

    // add P2 (dst proj + bias), then activation in log2 domain:
    //   sigmoid = rcp(1 + 2^-F')   softplus = ln2*log2(1+2^S')  (ln2 folded into inv_e)
    unsigned int pvv[8] = {pv0, pv1, pv2, pv3, pv4, pv5, pv6, pv7};
    half4 msgh[2];
#pragma unroll
    for (int ctl = 0; ctl < 2; ctl++) {
#pragma unroll
        for (int rr = 0; rr < 4; rr++) {
            U32H2 t; t.u = pvv[ctl * 4 + rr];
            float af = accf[ctl][rr] + (float)t.h.x;
            float as = accs[ctl][rr] + (float)t.h.y;
            float sg = __builtin_amdgcn_rcpf(1.0f + __builtin_amdgcn_exp2f(-af));
            float sp = __builtin_amdgcn_logf(1.0f + __builtin_amdgcn_exp2f(as));
            msgh[ctl][rr] = (_Float16)(sg * sp);
        }
    }
    // segment mask fragment: A[m=r16][k=quad*4+j] = (seg(k)==m) ? inv_deg(k)*ln2 : 0
    half4 am;
#pragma unroll
    for (int j = 0; j < 4; j++) {
        int sj = (segq >> (8 * j)) & 0xff;
        am[j] = (sj == r16) ? inv4[j] : (_Float16)0.0f;
    }
#pragma unroll
    for (int ctl = 0; ctl < 2; ctl++) {
        f32x4 red = __builtin_amdgcn_mfma_f32_16x16x16f16(am, msgh[ctl], zf, 0, 0, 0);
#pragma unroll
        for (int rr = 0; rr < 4; rr++) {
            int nd = wn4[rr];
            if (nd >= 0) atomicAdd(&x[(size_t)nd * GC + cb + ctl * 16 + r16], red[rr]);
        }
    }
}

// refill one frag set from window WW_ using prefetched SRC_
#define LOADSET(S0_, S1_, EE_, SRC_, WW_)                                            \
    S0_ = *(const half8*)(x16 + (size_t)(SRC_) * GC + quad * 8);                     \
    S1_ = *(const half8*)(x16 + (size_t)(SRC_) * GC + 32 + quad * 8);                \
    EE_ = *(const half8*)(ea + ((size_t)(WW_) * 16 + r16) * RBF + quad * 8);

// ---------- K5: window MFMA CGConv layer (3-deep data pipeline) ----------
__global__ __launch_bounds__(256, 3) void win_mfma_kernel(
    const _Float16* __restrict__ x16, const _Float16* __restrict__ ea,
    const int* __restrict__ csr_src, const int* __restrict__ csr_dst,
    const unsigned char* __restrict__ seg8, const int* __restrict__ wnode,
    const _Float16* __restrict__ inv_e, const unsigned int* __restrict__ P2u,
    const _Float16* __restrict__ wf16, const _Float16* __restrict__ ws16, // layer base [64][160]
    float* __restrict__ x)
{
    const int lane = threadIdx.x & 63;
    const int wid = __builtin_amdgcn_readfirstlane(threadIdx.x >> 6);
    const int quad = lane >> 4;
    const int r16 = lane & 15;
    const int wgid = blockIdx.x * 4 + wid;
    const int cb = (wgid & 1) * 32;
    int w = wgid >> 1;
    const int NSEQ = TILE_GRID * 2;

    // resident weight fragments: rows 64..159 (src + rbf), 3 K-tiles x 2 ctl halves
    half8 WGF[3][2], WGS[3][2];
#pragma unroll
    for (int ctl = 0; ctl < 2; ctl++) {
        const _Float16* wfp = wf16 + (size_t)(cb + ctl * 16 + r16) * 160 + 64 + quad * 8;
        const _Float16* wsp = ws16 + (size_t)(cb + ctl * 16 + r16) * 160 + 64 + quad * 8;
#pragma unroll
        for (int kt = 0; kt < 3; kt++) {
            WGF[kt][ctl] = *(const half8*)(wfp + kt * 32);
            WGS[kt][ctl] = *(const half8*)(wsp + kt * 32);
        }
    }

    // ---- prologue: sets A/B/C = windows w, w+N, w+2N; addr stage D = w+3N ----
    half8 AS0, AS1, AE, BS0, BS1, BE, CS0, CS1, CE;
    i32x4 d4A, d4B, d4C;
    int moffA, moffB, moffC;
    {
        int s_ = csr_src[w * 16 + r16];
        d4A = *(const i32x4*)(csr_dst + w * 16 + quad * 4);
        LOADSET(AS0, AS1, AE, s_, w);
        moffA = w * 16;
    }
    {
        int wB = w + NSEQ; if (wB >= NWIN) wB = NWIN - 1;
        int s_ = csr_src[wB * 16 + r16];
        d4B = *(const i32x4*)(csr_dst + wB * 16 + quad * 4);
        LOADSET(BS0, BS1, BE, s_, wB);
        moffB = wB * 16;
    }
    {
        int wCx = w + 2 * NSEQ; if (wCx >= NWIN) wCx = NWIN - 1;
        int s_ = csr_src[wCx * 16 + r16];
        d4C = *(const i32x4*)(csr_dst + wCx * 16 + quad * 4);
        LOADSET(CS0, CS1, CE, s_, wCx);
        moffC = wCx * 16;
    }
    int wD = w + 3 * NSEQ; if (wD >= NWIN) wD = NWIN - 1;
    int sD = csr_src[wD * 16 + r16];
    i32x4 d4D = *(const i32x4*)(csr_dst + wD * 16 + quad * 4);

    while (true) {
        compute_win(AS0, AS1, AE, d4A, moffA,
                    WGF, WGS, r16, quad, cb, seg8, wnode, inv_e, P2u, x);
        LOADSET(AS0, AS1, AE, sD, wD);
        d4A = d4D; moffA = wD * 16;
        wD += NSEQ; if (wD >= NWIN) wD = NWIN - 1;
        sD = csr_src[wD * 16 + r16];
        d4D = *(const i32x4*)(csr_dst + wD * 16 + quad * 4);
        w += NSEQ;
        if (w >= NWIN) break;

        compute_win(BS0, BS1, BE, d4B, moffB,
                    WGF, WGS, r16, quad, cb, seg8, wnode, inv_e, P2u, x);
        LOADSET(BS0, BS1, BE, sD, wD);
        d4B = d4D; moffB = wD * 16;
        wD += NSEQ; if (wD >= NWIN) wD = NWIN - 1;
        sD = csr_src[wD * 16 + r16];
        d4D = *(const i32x4*)(csr_dst + wD * 16 + quad * 4);
        w += NSEQ;
        if (w >= NWIN) break;

        compute_win(CS0, CS1, CE, d4C, moffC,
                    WGF, WGS, r16, quad, cb, seg8, wnode, inv_e, P2u, x);
        LOADSET(CS0, CS1, CE, sD, wD);
        d4C = d4D; moffC = wD * 16;
        wD += NSEQ; if (wD >= NWIN) wD = NWIN - 1;
        sD = csr_src[wD * 16 + r16];
        d4D = *(const i32x4*)(csr_dst + wD * 16 + quad * 4);
        w += NSEQ;
        if (w >= NWIN) break;
    }
}

// ---------- K6: BN stats ----------
__global__ __launch_bounds__(256) void stats_kernel(const float* __restrict__ x, float* __restrict__ stats)
{
    const int lane = threadIdx.x & 63;
    const int wid = threadIdx.x >> 6;
    int w = blockIdx.x * 4 + wid;
    float s1 = 0.0f, s2 = 0.0f;
    for (int n = w; n < N_NODES; n += 2048) {
        float v = x[(size_t)n * GC + lane];
        s1 += v;
        s2 = fmaf(v, v, s2);
    }
    __shared__ float rs1[4][64];
    __shared__ float rs2[4][64];
    rs1[wid][lane] = s1;
    rs2[wid][lane] = s2;
    __syncthreads();
    if (threadIdx.x < 64) {
        atomicAdd(&stats[lane], rs1[0][lane] + rs1[1][lane] + rs1[2][lane] + rs1[3][lane]);
    } else if (threadIdx.x < 128) {
        int c = threadIdx.x & 63;
        atomicAdd(&stats[64 + c], rs2[0][c] + rs2[1][c] + rs2[2][c] + rs2[3][c]);
    }
}

// ---------- K7: final batchnorm apply (layer 3 -> d_out) ----------
__global__ __launch_bounds__(256) void bn_kernel(
    const float* __restrict__ xn, const float* __restrict__ stats,
    const float* __restrict__ gamma, const float* __restrict__ beta,
    float* __restrict__ out)
{
    int i = blockIdx.x * 256 + threadIdx.x;
    int c4 = (i & 15) * 4;
    float4 v = ((const float4*)xn)[i];
    float vv[4] = {v.x, v.y, v.z, v.w};
    float o[4];
    const float invN = 1.0f / (float)N_NODES;
#pragma unroll
    for (int t = 0; t < 4; t++) {
        int c = c4 + t;
        float mu = stats[c] * invN;
        float var = stats[64 + c] * invN - mu * mu;
        float sc = gamma[c] * rsqrtf(var + BN_EPS);
        o[t] = (vv[t] - mu) * sc + beta[c];
    }
    ((float4*)out)[i] = make_float4(o[0], o[1], o[2], o[3]);
}

extern "C" void kernel_launch(void* const* d_in, const int* in_sizes, int n_in,
                              void* d_out, int out_size, void* d_ws, size_t ws_size,
                              hipStream_t stream)
{
    const int* atom_types = (const int*)d_in[0];
    const float* pos = (const float*)d_in[1];
    const int* edge_index = (const int*)d_in[2];
    const float* emb = (const float*)d_in[3];
    const float* pre_W = (const float*)d_in[4];
    const float* pre_b = (const float*)d_in[5];
    const float* Wf = (const float*)d_in[6];
    const float* bf = (const float*)d_in[7];
    const float* Ws = (const float*)d_in[8];
    const float* bs = (const float*)d_in[9];
    const float* gamma = (const float*)d_in[10];
    const float* beta = (const float*)d_in[11];
    const float* means = (const float*)d_in[12];
    const float* betas = (const float*)d_in[13];

    char* base = (char*)d_ws;
    char* p = base;
    auto alloc = [&](size_t bytes) -> char* {
        char* r = p;
        p += (bytes + 255) & ~(size_t)255;
        return r;
    };
    unsigned int* ea = (unsigned int*)alloc((size_t)N_EDGES * RBF * 2);    // 76.8 MB fp16
    float* x = (float*)alloc((size_t)N_NODES * GC * 4);                    // 25.6 MB
    _Float16* x16 = (_Float16*)alloc((size_t)N_NODES * GC * 2);            // 12.8 MB
    unsigned int* P2u = (unsigned int*)alloc((size_t)N_NODES * GC * 4);    // 25.6 MB {f,s} half2
    int* csr_src = (int*)alloc((size_t)N_EDGES * 4);                       // 4.8 MB
    int* csr_dst = (int*)alloc((size_t)N_EDGES * 4);                       // 4.8 MB
    int* rank = (int*)alloc((size_t)N_EDGES * 4);                          // 4.8 MB
    int* wnode = (int*)alloc((size_t)N_EDGES * 4);                         // 4.8 MB
    unsigned char* seg8 = (unsigned char*)alloc((size_t)N_EDGES);          // 1.2 MB
    _Float16* inv_e = (_Float16*)alloc((size_t)N_EDGES * 2);               // 2.4 MB
    _Float16* wf16 = (_Float16*)alloc((size_t)NLAYERS * GC * 160 * 2);     // 80 KB
    _Float16* ws16 = (_Float16*)alloc((size_t)NLAYERS * GC * 160 * 2);     // 80 KB
    int* row_st = (int*)alloc((size_t)(N_NODES + 1) * 4);
    float* inv_deg = (float*)alloc((size_t)N_NODES * 4);
    float* T = (float*)alloc((size_t)NATOM * GC * 4);
    int* bsums = (int*)alloc(512 * 4);
    const size_t ZR_INTS = (size_t)N_NODES + 128 * NLAYERS + 64;
    char* zr = alloc(ZR_INTS * 4);
    int* deg = (int*)zr;
    float* stats = (float*)(deg + N_NODES);

    if ((size_t)(p - base) > ws_size) return;  // diagnostic bail

    (void)hipMemsetAsync(zr, 0, ZR_INTS * 4, stream);

    const int EG = (N_EDGES + 255) / 256;
    degrank_kernel<<<EG, 256, 0, stream>>>(edge_index, deg, rank);
    scan_a_kernel<<<391, 256, 0, stream>>>(deg, bsums);
    scan_c_kernel<<<391, 256, 0, stream>>>(deg, bsums, row_st, inv_deg);
    scatter_perm_kernel<<<EG, 256, 0, stream>>>(edge_index, row_st, rank, csr_src, csr_dst);
    edge_post_kernel<<<EG, 256, 0, stream>>>(csr_src, csr_dst, pos, inv_deg, means, betas,
                                             ea, seg8, wnode, inv_e);
    prep_const_kernel<<<185, 256, 0, stream>>>(Wf, Ws, wf16, ws16, emb, pre_W, pre_b, T);
    initproj_kernel<<<N_NODES / 32, 256, 0, stream>>>(atom_types, T, x, x16,
                                                      wf16, ws16, bf, bs, P2u);

    for (int l = 0; l < NLAYERS; l++) {
        win_mfma_kernel<<<TILE_GRID, 256, 0, stream>>>(
            x16, (const _Float16*)ea, csr_src, csr_dst, seg8, wnode, inv_e, P2u,
            wf16 + (size_t)l * GC * 160, ws16 + (size_t)l * GC * 160, x);
        stats_kernel<<<512, 256, 0, stream>>>(x, stats + l * 128);
        if (l < NLAYERS - 1) {
            bnproj_kernel<<<N_NODES / 32, 256, 0, stream>>>(
                x, stats + l * 128, gamma + l * GC, beta + l * GC, x, x16,
                wf16 + (size_t)(l + 1) * GC * 160, ws16 + (size_t)(l + 1) * GC * 160,
                bf + (l + 1) * GC, bs + (l + 1) * GC, P2u);
        } else {
            bn_kernel<<<N_NODES * 16 / 256, 256, 0, stream>>>(
                x, stats + l * 128, gamma + l * GC, beta + l * GC, (float*)d_out);
        }
    }
}

// Round 11
// 733.710 us; speedup vs baseline: 1.1148x; 1.0390x over previous
//
#include <hip/hip_runtime.h>
#include <math.h>

#define N_NODES 100000
#define N_EDGES 1200000
#define GC 64
#define RBF 32
#define NLAYERS 4
#define NF 92
#define NATOM 100
#define BN_EPS 1e-5f
#define TILE_GRID 2048
#define NWIN (N_EDGES / 16)     // 75000 windows, exact (E % 16 == 0)
#define EG ((N_EDGES + 255) / 256)
#define NODE_BLOCKS (N_NODES / 32)
#define LOG2E 1.44269504f
#define LN2 0.69314718f

typedef _Float16 half8 __attribute__((ext_vector_type(8)));
typedef _Float16 half4 __attribute__((ext_vector_type(4)));
typedef _Float16 half2v __attribute__((ext_vector_type(2)));
typedef float f32x4 __attribute__((ext_vector_type(4)));
typedef int i32x4 __attribute__((ext_vector_type(4)));
union U32H2 { unsigned int u; half2v h; };

// ---------- K1 (merged): degree histogram + rank  |  weight cvt + atom table ----------
__global__ __launch_bounds__(256) void degrank_prep_kernel(
    const int* __restrict__ ei, int* __restrict__ deg, int* __restrict__ rank,
    const float* __restrict__ Wf, const float* __restrict__ Ws,
    _Float16* __restrict__ wf16, _Float16* __restrict__ ws16,
    const float* __restrict__ emb, const float* __restrict__ pre_W,
    const float* __restrict__ pre_b, float* __restrict__ T)
{
    int b = blockIdx.x;
    if (b < EG) {
        int e = b * 256 + threadIdx.x;
        if (e < N_EDGES) rank[e] = atomicAdd(&deg[ei[N_EDGES + e]], 1);
        return;
    }
    b -= EG;
    if (b < 160) {
        int i = b * 256 + threadIdx.x;   // NLAYERS*160*64 = 40960 exact
        int l = i / (160 * GC);
        int r = i - l * 160 * GC;
        int k = r >> 6;
        int col = r & 63;
        size_t o = ((size_t)l * GC + col) * 160 + k;
        wf16[o] = (_Float16)(Wf[i] * LOG2E);
        ws16[o] = (_Float16)(Ws[i] * LOG2E);
    } else {
        int a = (b - 160) * 4 + (threadIdx.x >> 6);
        int c = threadIdx.x & 63;
        if (a < NATOM) {
            float acc = pre_b[c];
            for (int k = 0; k < NF; k++) acc = fmaf(emb[a * NF + k], pre_W[k * GC + c], acc);
            T[a * GC + c] = fmaxf(acc, 0.0f);
        }
    }
}

// ---------- scan ----------
__global__ __launch_bounds__(256) void scan_a_kernel(const int* __restrict__ deg, int* __restrict__ bsums)
{
    __shared__ int sm[256];
    int tid = threadIdx.x;
    int i = blockIdx.x * 256 + tid;
    int v = (i < N_NODES) ? deg[i] : 0;
    sm[tid] = v;
    __syncthreads();
    for (int s = 128; s > 0; s >>= 1) {
        if (tid < s) sm[tid] += sm[tid + s];
        __syncthreads();
    }
    if (tid == 0) bsums[blockIdx.x] = sm[0];
}

// scan_c with fused block-offset reduction
__global__ __launch_bounds__(256) void scan_c_kernel(
    const int* __restrict__ deg, const int* __restrict__ bsums,
    int* __restrict__ row_st, float* __restrict__ inv_deg)
{
    __shared__ int sm[256];
    int tid = threadIdx.x;
    int acc = 0;
    if (tid < blockIdx.x) acc = bsums[tid];
    int t2 = tid + 256;
    if (t2 < blockIdx.x) acc += bsums[t2];
    sm[tid] = acc;
    __syncthreads();
    for (int s = 128; s > 0; s >>= 1) {
        if (tid < s) sm[tid] += sm[tid + s];
        __syncthreads();
    }
    int boff = sm[0];
    __syncthreads();
    int i = blockIdx.x * 256 + tid;
    int v = (i < N_NODES) ? deg[i] : 0;
    sm[tid] = v;
    __syncthreads();
    for (int off = 1; off < 256; off <<= 1) {
        int t = (tid >= off) ? sm[tid - off] : 0;
        __syncthreads();
        sm[tid] += t;
        __syncthreads();
    }
    if (i <= N_NODES) row_st[i] = boff + sm[tid] - v;  // exclusive
    if (i < N_NODES) inv_deg[i] = (v > 0) ? (1.0f / (float)v) : 0.0f;
}

// ---------- K2a: atomic-free scatter into CSR order (single int2 scattered store) ----------
__global__ __launch_bounds__(256) void scatter_perm_kernel(
    const int* __restrict__ ei, const int* __restrict__ row_st,
    const int* __restrict__ rank, int2* __restrict__ csr_sd)
{
    int e = blockIdx.x * 256 + threadIdx.x;
    if (e >= N_EDGES) return;
    int s = ei[e];
    int d = ei[N_EDGES + e];
    csr_sd[row_st[d] + rank[e]] = make_int2(s, d);
}

// ---------- shared proj body: P2[node][ch] = {f,s} half2, bias*log2e folded ----------
static __device__ __forceinline__ void proj_mfma16(
    const _Float16* __restrict__ wf, const _Float16* __restrict__ ws,
    const float* __restrict__ bfv, const float* __restrict__ bsv,
    const half8 Bn[2], int cb, int node, unsigned int* __restrict__ P2u)
{
    const int lane = threadIdx.x & 63;
    const int quad = lane >> 4;
    const int r16 = lane & 15;
    f32x4 accf[2], accs[2];
#pragma unroll
    for (int sub = 0; sub < 2; sub++) {
        accf[sub] = (f32x4){0.f, 0.f, 0.f, 0.f};
        accs[sub] = (f32x4){0.f, 0.f, 0.f, 0.f};
    }
#pragma unroll
    for (int kt = 0; kt < 2; kt++) {
#pragma unroll
        for (int sub = 0; sub < 2; sub++) {
            int chan = cb + sub * 16 + r16;
            half8 a = *(const half8*)(wf + (size_t)chan * 160 + kt * 32 + quad * 8);
            half8 b = *(const half8*)(ws + (size_t)chan * 160 + kt * 32 + quad * 8);
            accf[sub] = __builtin_amdgcn_mfma_f32_16x16x32_f16(a, Bn[kt], accf[sub], 0, 0, 0);
            accs[sub] = __builtin_amdgcn_mfma_f32_16x16x32_f16(b, Bn[kt], accs[sub], 0, 0, 0);
        }
    }
#pragma unroll
    for (int sub = 0; sub < 2; sub++) {
        float4 bf4 = *(const float4*)(bfv + cb + sub * 16 + quad * 4);
        float4 bs4 = *(const float4*)(bsv + cb + sub * 16 + quad * 4);
        half8 h = { (_Float16)(accf[sub][0] + bf4.x * LOG2E), (_Float16)(accs[sub][0] + bs4.x * LOG2E),
                    (_Float16)(accf[sub][1] + bf4.y * LOG2E), (_Float16)(accs[sub][1] + bs4.y * LOG2E),
                    (_Float16)(accf[sub][2] + bf4.z * LOG2E), (_Float16)(accs[sub][2] + bs4.z * LOG2E),
                    (_Float16)(accf[sub][3] + bf4.w * LOG2E), (_Float16)(accs[sub][3] + bs4.w * LOG2E) };
        *(half8*)(P2u + (size_t)node * GC + cb + sub * 16 + quad * 4) = h;
    }
}

// ---------- K2b (merged): split+RBF+window-metadata  |  xinit+proj(layer0) ----------
__global__ __launch_bounds__(256) void edgepost_initproj_kernel(
    const int2* __restrict__ csr_sd, const float* __restrict__ pos,
    const float* __restrict__ inv_deg,
    const float* __restrict__ means, const float* __restrict__ betas,
    int* __restrict__ csr_src, int* __restrict__ csr_dst,
    unsigned int* __restrict__ ea,
    unsigned char* __restrict__ seg8, int* __restrict__ wnode,
    _Float16* __restrict__ inv_e,
    const int* __restrict__ atom_types, const float* __restrict__ T,
    float* __restrict__ x, _Float16* __restrict__ x16,
    const _Float16* __restrict__ wf, const _Float16* __restrict__ ws,
    const float* __restrict__ bfv, const float* __restrict__ bsv,
    unsigned int* __restrict__ P2u)
{
    __shared__ int sdst[256];
    __shared__ _Float16 lx[32 * 72];

    if (blockIdx.x < EG) {
        // ---- edge part ----
        int t = blockIdx.x * 256 + threadIdx.x;
        if (t < N_EDGES) {
            int2 v = csr_sd[t];
            int s = v.x, d = v.y;
            csr_src[t] = s;
            csr_dst[t] = d;
            sdst[threadIdx.x] = d;
            inv_e[t] = (_Float16)(inv_deg[d] * LN2);

            float dx = pos[s * 3 + 0] - pos[d * 3 + 0];
            float dy = pos[s * 3 + 1] - pos[d * 3 + 1];
            float dz = pos[s * 3 + 2] - pos[d * 3 + 2];
            float dist = sqrtf(dx * dx + dy * dy + dz * dz + 1e-12f);
            float cut = 0.0f;
            if (dist < 5.0f) cut = 0.5f * (__cosf(dist * 0.6283185307179586f) + 1.0f);
            float ex = __expf(-dist);
            union { _Float16 h[32]; uint4 u[4]; } pk;
#pragma unroll
            for (int k = 0; k < 32; k++) {
                float vk = ex - means[k];
                pk.h[k] = (_Float16)(cut * __expf(-betas[k] * vk * vk));
            }
            uint4* op = (uint4*)(ea + (size_t)t * 16);
            op[0] = pk.u[0];
            op[1] = pk.u[1];
            op[2] = pk.u[2];
            op[3] = pk.u[3];
        }
        __syncthreads();
        if (threadIdx.x < 16) {
            int w0 = blockIdx.x * 16 + threadIdx.x;      // global window id
            if ((size_t)w0 * 16 < N_EDGES) {
                int lb = threadIdx.x * 16;
                int gb = w0 * 16;
                int prev = -1, sg = -1;
                for (int k = 0; k < 16; k++) {
                    int dd = sdst[lb + k];
                    if (dd != prev) { sg++; prev = dd; wnode[gb + sg] = dd; }
                    seg8[gb + k] = (unsigned char)sg;
                }
                for (int m = sg + 1; m < 16; m++) wnode[gb + m] = -1;
            }
        }
        return;
    }

    // ---- node part: xinit + proj layer 0 ----
    const int nb = (blockIdx.x - EG) * 32;
#pragma unroll
    for (int rep = 0; rep < 2; rep++) {
        int g = rep * 256 + threadIdx.x;        // granule within block: 0..511
        int gi = (blockIdx.x - EG) * 512 + g;   // global float4 granule
        int node = g >> 4;                      // 0..31
        int c4 = (g & 15) * 4;
        int a = atom_types[nb + node];
        float4 v = ((const float4*)T)[a * 16 + (g & 15)];
        ((float4*)x)[gi] = v;
        half4 h = { (_Float16)v.x, (_Float16)v.y, (_Float16)v.z, (_Float16)v.w };
        ((half4*)x16)[gi] = h;
        *(half4*)(lx + node * 72 + c4) = h;
    }
    __syncthreads();

    const int lane = threadIdx.x & 63;
    const int wid = threadIdx.x >> 6;
    const int quad = lane >> 4;
    const int r16 = lane & 15;
    const int cb = (wid & 1) * 32;
    const int tn = (wid >> 1) * 16 + r16;       // node within block's 32
    half8 Bn[2];
    Bn[0] = *(const half8*)(lx + tn * 72 + quad * 8);
    Bn[1] = *(const half8*)(lx + tn * 72 + 32 + quad * 8);
    proj_mfma16(wf, ws, bfv, bsv, Bn, cb, nb + tn, P2u);
}

// ---------- K_bnproj: BN apply (layer l) fused with proj (layer l+1) ----------
__global__ __launch_bounds__(256) void bnproj_kernel(
    const float* __restrict__ xn, const float* __restrict__ stats,
    const float* __restrict__ gamma, const float* __restrict__ beta,
    float* __restrict__ xout, _Float16* __restrict__ x16,
    const _Float16* __restrict__ wf, const _Float16* __restrict__ ws,  // next layer
    const float* __restrict__ bfv, const float* __restrict__ bsv,      // next layer
    unsigned int* __restrict__ P2u)
{
    __shared__ _Float16 lx[32 * 72];   // 72-half row pad -> free 2-way LDS banks
    const int nb = blockIdx.x * 32;
    const float invN = 1.0f / (float)N_NODES;

#pragma unroll
    for (int rep = 0; rep < 2; rep++) {
        int g = rep * 256 + threadIdx.x;        // granule within block: 0..511
        int gi = blockIdx.x * 512 + g;          // global float4 granule
        int node = g >> 4;                      // 0..31
        int c4 = (g & 15) * 4;
        float4 v = ((const float4*)xn)[gi];
        float vv[4] = {v.x, v.y, v.z, v.w};
        float o[4];
#pragma unroll
        for (int t = 0; t < 4; t++) {
            int c = c4 + t;
            float mu = stats[c] * invN;
            float var = stats[64 + c] * invN - mu * mu;
            float sc = gamma[c] * rsqrtf(var + BN_EPS);
            o[t] = (vv[t] - mu) * sc + beta[c];
        }
        ((float4*)xout)[gi] = make_float4(o[0], o[1], o[2], o[3]);
        half4 h = { (_Float16)o[0], (_Float16)o[1], (_Float16)o[2], (_Float16)o[3] };
        ((half4*)x16)[gi] = h;
        *(half4*)(lx + node * 72 + c4) = h;
    }
    __syncthreads();

    const int lane = threadIdx.x & 63;
    const int wid = threadIdx.x >> 6;
    const int quad = lane >> 4;
    const int r16 = lane & 15;
    const int cb = (wid & 1) * 32;
    const int tn = (wid >> 1) * 16 + r16;       // node within block's 32
    half8 Bn[2];
    Bn[0] = *(const half8*)(lx + tn * 72 + quad * 8);
    Bn[1] = *(const half8*)(lx + tn * 72 + 32 + quad * 8);
    proj_mfma16(wf, ws, bfv, bsv, Bn, cb, nb + tn, P2u);
}

// ---------- window compute body ----------
static __device__ __forceinline__ void compute_win(
    half8 S0, half8 S1, half8 E, i32x4 d4, int moff,
    const half8 (&WGF)[3][2], const half8 (&WGS)[3][2],
    int r16, int quad, int cb,
    const unsigned char* __restrict__ seg8, const int* __restrict__ wnode,
    const _Float16* __restrict__ inv_e, const unsigned int* __restrict__ P2u,
    float* __restrict__ x)
{
    // issue gathers/meta now; consumers are after the MFMA block
    unsigned int pv0, pv1, pv2, pv3, pv4, pv5, pv6, pv7;
    {
        const unsigned int* p0 = P2u + (size_t)d4[0] * GC + cb + r16;
        const unsigned int* p1 = P2u + (size_t)d4[1] * GC + cb + r16;
        const unsigned int* p2 = P2u + (size_t)d4[2] * GC + cb + r16;
        const unsigned int* p3 = P2u + (size_t)d4[3] * GC + cb + r16;
        pv0 = p0[0];  pv4 = p0[16];
        pv1 = p1[0];  pv5 = p1[16];
        pv2 = p2[0];  pv6 = p2[16];
        pv3 = p3[0];  pv7 = p3[16];
    }
    unsigned int segq = *(const unsigned int*)(seg8 + moff + quad * 4);
    i32x4 wn4 = *(const i32x4*)(wnode + moff + quad * 4);
    half4 inv4 = *(const half4*)(inv_e + moff + quad * 4);

    const f32x4 zf = (f32x4){0.0f, 0.0f, 0.0f, 0.0f};
    f32x4 accf[2], accs[2];
    __builtin_amdgcn_s_setprio(1);
#pragma unroll
    for (int ctl = 0; ctl < 2; ctl++) {
        accf[ctl] = __builtin_amdgcn_mfma_f32_16x16x32_f16(S0, WGF[0][ctl], zf, 0, 0, 0);
        accs[ctl] = __builtin_amdgcn_mfma_f32_16x16x32_f16(S0, WGS[0][ctl], zf, 0, 0, 0);
        accf[ctl] = __builtin_amdgcn_mfma_f32_16x16x32_f16(S1, WGF[1][ctl], accf[ctl], 0, 0, 0);
        accs[ctl] = __builtin_amdgcn_mfma_f32_16x16x32_f16(S1, WGS[1][ctl], accs[ctl], 0, 0, 0);
        accf[ctl] = __builtin_amdgcn_mfma_f32_16x16x32_f16(E,  WGF[2][ctl], accf[ctl], 0, 0, 0);
        accs[ctl] = __builtin_amdgcn_mfma_f32_16x16x32_f16(E,  WGS[2][ctl], accs[ctl], 0, 0, 0);
    }
    __builtin_amdgcn_s_setprio(0);

    // add P2 (dst proj + bias), then activation in log2 domain:
    //   sigmoid = rcp(1 + 2^-F')   softplus = ln2*log2(1+2^S')  (ln2 folded into inv_e)
    unsigned int pvv[8] = {pv0, pv1, pv2, pv3, pv4, pv5, pv6, pv7};
    half4 msgh[2];
#pragma unroll
    for (int ctl = 0; ctl < 2; ctl++) {
#pragma unroll
        for (int rr = 0; rr < 4; rr++) {
            U32H2 t; t.u = pvv[ctl * 4 + rr];
            float af = accf[ctl][rr] + (float)t.h.x;
            float as = accs[ctl][rr] + (float)t.h.y;
            float sg = __builtin_amdgcn_rcpf(1.0f + __builtin_amdgcn_exp2f(-af));
            float sp = __builtin_amdgcn_logf(1.0f + __builtin_amdgcn_exp2f(as));
            msgh[ctl][rr] = (_Float16)(sg * sp);
        }
    }
    // segment mask fragment: A[m=r16][k=quad*4+j] = (seg(k)==m) ? inv_deg(k)*ln2 : 0
    half4 am;
#pragma unroll
    for (int j = 0; j < 4; j++) {
        int sj = (segq >> (8 * j)) & 0xff;
        am[j] = (sj == r16) ? inv4[j] : (_Float16)0.0f;
    }
#pragma unroll
    for (int ctl = 0; ctl < 2; ctl++) {
        f32x4 red = __builtin_amdgcn_mfma_f32_16x16x16f16(am, msgh[ctl], zf, 0, 0, 0);
#pragma unroll
        for (int rr = 0; rr < 4; rr++) {
            int nd = wn4[rr];
            if (nd >= 0) atomicAdd(&x[(size_t)nd * GC + cb + ctl * 16 + r16], red[rr]);
        }
    }
}

// refill one frag set from window WW_ using prefetched SRC_
#define LOADSET(S0_, S1_, EE_, SRC_, WW_)                                            \
    S0_ = *(const half8*)(x16 + (size_t)(SRC_) * GC + quad * 8);                     \
    S1_ = *(const half8*)(x16 + (size_t)(SRC_) * GC + 32 + quad * 8);                \
    EE_ = *(const half8*)(ea + ((size_t)(WW_) * 16 + r16) * RBF + quad * 8);

// ---------- K5: window MFMA CGConv layer (3-deep data pipeline) ----------
__global__ __launch_bounds__(256, 3) void win_mfma_kernel(
    const _Float16* __restrict__ x16, const _Float16* __restrict__ ea,
    const int* __restrict__ csr_src, const int* __restrict__ csr_dst,
    const unsigned char* __restrict__ seg8, const int* __restrict__ wnode,
    const _Float16* __restrict__ inv_e, const unsigned int* __restrict__ P2u,
    const _Float16* __restrict__ wf16, const _Float16* __restrict__ ws16, // layer base [64][160]
    float* __restrict__ x)
{
    const int lane = threadIdx.x & 63;
    const int wid = __builtin_amdgcn_readfirstlane(threadIdx.x >> 6);
    const int quad = lane >> 4;
    const int r16 = lane & 15;
    const int wgid = blockIdx.x * 4 + wid;
    const int cb = (wgid & 1) * 32;
    int w = wgid >> 1;
    const int NSEQ = TILE_GRID * 2;

    // resident weight fragments: rows 64..159 (src + rbf), 3 K-tiles x 2 ctl halves
    half8 WGF[3][2], WGS[3][2];
#pragma unroll
    for (int ctl = 0; ctl < 2; ctl++) {
        const _Float16* wfp = wf16 + (size_t)(cb + ctl * 16 + r16) * 160 + 64 + quad * 8;
        const _Float16* wsp = ws16 + (size_t)(cb + ctl * 16 + r16) * 160 + 64 + quad * 8;
#pragma unroll
        for (int kt = 0; kt < 3; kt++) {
            WGF[kt][ctl] = *(const half8*)(wfp + kt * 32);
            WGS[kt][ctl] = *(const half8*)(wsp + kt * 32);
        }
    }

    // ---- prologue: sets A/B/C = windows w, w+N, w+2N; addr stage D = w+3N ----
    half8 AS0, AS1, AE, BS0, BS1, BE, CS0, CS1, CE;
    i32x4 d4A, d4B, d4C;
    int moffA, moffB, moffC;
    {
        int s_ = csr_src[w * 16 + r16];
        d4A = *(const i32x4*)(csr_dst + w * 16 + quad * 4);
        LOADSET(AS0, AS1, AE, s_, w);
        moffA = w * 16;
    }
    {
        int wB = w + NSEQ; if (wB >= NWIN) wB = NWIN - 1;
        int s_ = csr_src[wB * 16 + r16];
        d4B = *(const i32x4*)(csr_dst + wB * 16 + quad * 4);
        LOADSET(BS0, BS1, BE, s_, wB);
        moffB = wB * 16;
    }
    {
        int wCx = w + 2 * NSEQ; if (wCx >= NWIN) wCx = NWIN - 1;
        int s_ = csr_src[wCx * 16 + r16];
        d4C = *(const i32x4*)(csr_dst + wCx * 16 + quad * 4);
        LOADSET(CS0, CS1, CE, s_, wCx);
        moffC = wCx * 16;
    }
    int wD = w + 3 * NSEQ; if (wD >= NWIN) wD = NWIN - 1;
    int sD = csr_src[wD * 16 + r16];
    i32x4 d4D = *(const i32x4*)(csr_dst + wD * 16 + quad * 4);

    while (true) {
        compute_win(AS0, AS1, AE, d4A, moffA,
                    WGF, WGS, r16, quad, cb, seg8, wnode, inv_e, P2u, x);
        LOADSET(AS0, AS1, AE, sD, wD);
        d4A = d4D; moffA = wD * 16;
        wD += NSEQ; if (wD >= NWIN) wD = NWIN - 1;
        sD = csr_src[wD * 16 + r16];
        d4D = *(const i32x4*)(csr_dst + wD * 16 + quad * 4);
        w += NSEQ;
        if (w >= NWIN) break;

        compute_win(BS0, BS1, BE, d4B, moffB,
                    WGF, WGS, r16, quad, cb, seg8, wnode, inv_e, P2u, x);
        LOADSET(BS0, BS1, BE, sD, wD);
        d4B = d4D; moffB = wD * 16;
        wD += NSEQ; if (wD >= NWIN) wD = NWIN - 1;
        sD = csr_src[wD * 16 + r16];
        d4D = *(const i32x4*)(csr_dst + wD * 16 + quad * 4);
        w += NSEQ;
        if (w >= NWIN) break;

        compute_win(CS0, CS1, CE, d4C, moffC,
                    WGF, WGS, r16, quad, cb, seg8, wnode, inv_e, P2u, x);
        LOADSET(CS0, CS1, CE, sD, wD);
        d4C = d4D; moffC = wD * 16;
        wD += NSEQ; if (wD >= NWIN) wD = NWIN - 1;
        sD = csr_src[wD * 16 + r16];
        d4D = *(const i32x4*)(csr_dst + wD * 16 + quad * 4);
        w += NSEQ;
        if (w >= NWIN) break;
    }
}

// ---------- K6: BN stats ----------
__global__ __launch_bounds__(256) void stats_kernel(const float* __restrict__ x, float* __restrict__ stats)
{
    const int lane = threadIdx.x & 63;
    const int wid = threadIdx.x >> 6;
    int w = blockIdx.x * 4 + wid;
    float s1 = 0.0f, s2 = 0.0f;
    for (int n = w; n < N_NODES; n += 2048) {
        float v = x[(size_t)n * GC + lane];
        s1 += v;
        s2 = fmaf(v, v, s2);
    }
    __shared__ float rs1[4][64];
    __shared__ float rs2[4][64];
    rs1[wid][lane] = s1;
    rs2[wid][lane] = s2;
    __syncthreads();
    if (threadIdx.x < 64) {
        atomicAdd(&stats[lane], rs1[0][lane] + rs1[1][lane] + rs1[2][lane] + rs1[3][lane]);
    } else if (threadIdx.x < 128) {
        int c = threadIdx.x & 63;
        atomicAdd(&stats[64 + c], rs2[0][c] + rs2[1][c] + rs2[2][c] + rs2[3][c]);
    }
}

// ---------- K7: final batchnorm apply (layer 3 -> d_out) ----------
__global__ __launch_bounds__(256) void bn_kernel(
    const float* __restrict__ xn, const float* __restrict__ stats,
    const float* __restrict__ gamma, const float* __restrict__ beta,
    float* __restrict__ out)
{
    int i = blockIdx.x * 256 + threadIdx.x;
    int c4 = (i & 15) * 4;
    float4 v = ((const float4*)xn)[i];
    float vv[4] = {v.x, v.y, v.z, v.w};
    float o[4];
    const float invN = 1.0f / (float)N_NODES;
#pragma unroll
    for (int t = 0; t < 4; t++) {
        int c = c4 + t;
        float mu = stats[c] * invN;
        float var = stats[64 + c] * invN - mu * mu;
        float sc = gamma[c] * rsqrtf(var + BN_EPS);
        o[t] = (vv[t] - mu) * sc + beta[c];
    }
    ((float4*)out)[i] = make_float4(o[0], o[1], o[2], o[3]);
}

extern "C" void kernel_launch(void* const* d_in, const int* in_sizes, int n_in,
                              void* d_out, int out_size, void* d_ws, size_t ws_size,
                              hipStream_t stream)
{
    const int* atom_types = (const int*)d_in[0];
    const float* pos = (const float*)d_in[1];
    const int* edge_index = (const int*)d_in[2];
    const float* emb = (const float*)d_in[3];
    const float* pre_W = (const float*)d_in[4];
    const float* pre_b = (const float*)d_in[5];
    const float* Wf = (const float*)d_in[6];
    const float* bf = (const float*)d_in[7];
    const float* Ws = (const float*)d_in[8];
    const float* bs = (const float*)d_in[9];
    const float* gamma = (const float*)d_in[10];
    const float* beta = (const float*)d_in[11];
    const float* means = (const float*)d_in[12];
    const float* betas = (const float*)d_in[13];

    char* base = (char*)d_ws;
    char* p = base;
    auto alloc = [&](size_t bytes) -> char* {
        char* r = p;
        p += (bytes + 255) & ~(size_t)255;
        return r;
    };
    unsigned int* ea = (unsigned int*)alloc((size_t)N_EDGES * RBF * 2);    // 76.8 MB fp16
    float* x = (float*)alloc((size_t)N_NODES * GC * 4);                    // 25.6 MB
    _Float16* x16 = (_Float16*)alloc((size_t)N_NODES * GC * 2);            // 12.8 MB
    unsigned int* P2u = (unsigned int*)alloc((size_t)N_NODES * GC * 4);    // 25.6 MB {f,s} half2
    int2* csr_sd = (int2*)alloc((size_t)N_EDGES * 8);                      // 9.6 MB
    int* csr_src = (int*)alloc((size_t)N_EDGES * 4);                       // 4.8 MB
    int* csr_dst = (int*)alloc((size_t)N_EDGES * 4);                       // 4.8 MB
    int* rank = (int*)alloc((size_t)N_EDGES * 4);                          // 4.8 MB
    int* wnode = (int*)alloc((size_t)N_EDGES * 4);                         // 4.8 MB
    unsigned char* seg8 = (unsigned char*)alloc((size_t)N_EDGES);          // 1.2 MB
    _Float16* inv_e = (_Float16*)alloc((size_t)N_EDGES * 2);               // 2.4 MB
    _Float16* wf16 = (_Float16*)alloc((size_t)NLAYERS * GC * 160 * 2);     // 80 KB
    _Float16* ws16 = (_Float16*)alloc((size_t)NLAYERS * GC * 160 * 2);     // 80 KB
    int* row_st = (int*)alloc((size_t)(N_NODES + 1) * 4);
    float* inv_deg = (float*)alloc((size_t)N_NODES * 4);
    float* T = (float*)alloc((size_t)NATOM * GC * 4);
    int* bsums = (int*)alloc(512 * 4);
    const size_t ZR_INTS = (size_t)N_NODES + 128 * NLAYERS + 64;
    char* zr = alloc(ZR_INTS * 4);
    int* deg = (int*)zr;
    float* stats = (float*)(deg + N_NODES);

    if ((size_t)(p - base) > ws_size) return;  // diagnostic bail

    (void)hipMemsetAsync(zr, 0, ZR_INTS * 4, stream);

    degrank_prep_kernel<<<EG + 185, 256, 0, stream>>>(
        edge_index, deg, rank, Wf, Ws, wf16, ws16, emb, pre_W, pre_b, T);
    scan_a_kernel<<<391, 256, 0, stream>>>(deg, bsums);
    scan_c_kernel<<<391, 256, 0, stream>>>(deg, bsums, row_st, inv_deg);
    scatter_perm_kernel<<<EG, 256, 0, stream>>>(edge_index, row_st, rank, csr_sd);
    edgepost_initproj_kernel<<<EG + NODE_BLOCKS, 256, 0, stream>>>(
        csr_sd, pos, inv_deg, means, betas, csr_src, csr_dst, ea, seg8, wnode, inv_e,
        atom_types, T, x, x16, wf16, ws16, bf, bs, P2u);

    for (int l = 0; l < NLAYERS; l++) {
        win_mfma_kernel<<<TILE_GRID, 256, 0, stream>>>(
            x16, (const _Float16*)ea, csr_src, csr_dst, seg8, wnode, inv_e, P2u,
            wf16 + (size_t)l * GC * 160, ws16 + (size_t)l * GC * 160, x);
        stats_kernel<<<512, 256, 0, stream>>>(x, stats + l * 128);
        if (l < NLAYERS - 1) {
            bnproj_kernel<<<NODE_BLOCKS, 256, 0, stream>>>(
                x, stats + l * 128, gamma + l * GC, beta + l * GC, x, x16,
                wf16 + (size_t)(l + 1) * GC * 160, ws16 + (size_t)(l + 1) * GC * 160,
                bf + (l + 1) * GC, bs + (l + 1) * GC, P2u);
        } else {
            bn_kernel<<<N_NODES * 16 / 256, 256, 0, stream>>>(
                x, stats + l * 128, gamma + l * GC, beta + l * GC, (float*)d_out);
        }
    }
}